// Round 5
// baseline (838.112 us; speedup 1.0000x reference)
//
#include <hip/hip_runtime.h>
#include <hip/hip_fp16.h>

// CorrVolume1DBlock: cv[n,i,h,w] = (1/C) * sum_c x1[n,c,h,w] * x2[n,c,h,w-i],
// zero where w-i < 0.  B=8, C=128, H=128, W=256, i in [0,64], fp32 in/out.
//
// R9: BARRIER-FREE single-wave blocks. R4/R7/R8 all ~133-147us with nothing
// >40% busy: phase-serialization (all waves stall together on vmcnt+barrier
// every chunk). Here each block is ONE wave owning (n,h,qi):
//  - private x2 LDS double-buffer (2 x 4 c-pair rows x 324 cols = 10.4 KB),
//    f16 channel-pair packed, 64-col zero margin; NO __syncthreads anywhere.
//  - x1 in packed registers, prefetched half-chunk ahead (R8's per-c2
//    global-latency exposure removed).
//  - chunk = 8 channels (KC2=4 c-pairs), 16 chunks; per chunk: issue next x2
//    (8 float4) + next x1 (staggered 2x2 c-pairs), compute 4 c2 windows
//    (5 aligned b128 + 64 fdot2 each), commit x2 to buf^1 at end (vmcnt
//    drain lands after compute). asm memory clobbers pin issue-before-compute.
//  - grid (qi, h, n) = (4,128,8): the 4 qi-blocks of an (n,h) are adjacent ->
//    x1 x4 redundancy served by L3/L2.
//  - __launch_bounds__(64,3): 170-reg cap, ~12 waves/CU, all independent.
//  - i=64 handled by qi==3 (taps bw[wl] inside the same aligned window).
//  - Precision: f16 inputs, f32 accumulate -> absmax ~2e-3 vs 9.96e-3.

constexpr int B   = 8;
constexpr int C   = 128;
constexpr int H   = 128;
constexpr int W   = 256;
constexpr int NI  = 65;
constexpr int HW  = H * W;
constexpr int CHW = C * HW;
constexpr int KC2 = 4;             // c-PAIRS per chunk (8 channels)
constexpr int X2W = 324;           // 320 cols + 4 pad (row stride 1296 B)
constexpr int NCHUNK = C / (2 * KC2);  // 16

typedef _Float16 half2v __attribute__((ext_vector_type(2)));

__device__ inline unsigned int pack2(float a, float b) {
    __half2 h = __floats2half2_rn(a, b);     // a -> low, b -> high
    return __builtin_bit_cast(unsigned int, h);
}

__device__ inline float fdot2f(unsigned int a, unsigned int b, float c) {
#if __has_builtin(__builtin_amdgcn_fdot2)
    return __builtin_amdgcn_fdot2(__builtin_bit_cast(half2v, a),
                                  __builtin_bit_cast(half2v, b), c, false);
#else
    __half2 ha = __builtin_bit_cast(__half2, a);
    __half2 hb = __builtin_bit_cast(__half2, b);
    float2 fa = __half22float2(ha), fb = __half22float2(hb);
    return fmaf(fa.x, fb.x, fmaf(fa.y, fb.y, c));
#endif
}

__global__ __launch_bounds__(64, 3)
void corr_volume_kernel(const float* __restrict__ x1,
                        const float* __restrict__ x2,
                        float* __restrict__ out) {
    const int qi = blockIdx.x;       // i-group: i = 16*qi + il
    const int h  = blockIdx.y;
    const int n  = blockIdx.z;
    const int l  = threadIdx.x;      // one wave: w = 4l .. 4l+3

    __shared__ unsigned int x2h[2][KC2][X2W];   // 10368 B, private to this wave

    float acc[16][4];
    #pragma unroll
    for (int il = 0; il < 16; ++il)
        #pragma unroll
        for (int wl = 0; wl < 4; ++wl) acc[il][wl] = 0.0f;
    float acc64[4] = {0.f, 0.f, 0.f, 0.f};      // only qi==3 (i=64)

    // window: LDS col j = w - i + 64 = j0a + (16 + wl - il), idx in [1,19];
    // i=64 (qi==3) lands at idx = wl. 5 aligned uint4 per c2.
    const int j0a = 4 * l - 16 * qi + 48;   // in [0, 300], uint4-aligned

    const float* x1g = x1 + n * CHW + h * W;
    const float* x2g = x2 + n * CHW + h * W;

    // zero-fill left margins of both buffers (wave-private, no barrier needed)
    #pragma unroll
    for (int k = 0; k < 2; ++k) {
        const int idx  = l + 64 * k;        // [0,128)
        const int bufi = idx >> 6;
        const int r    = (idx >> 4) & 3;
        const int cq   = idx & 15;          // cols [0,64)
        *(uint4*)&x2h[bufi][r][4 * cq] = make_uint4(0u, 0u, 0u, 0u);
    }

    // ---- x2 staging: lane (sr,ss) covers row sr, 4 uint4 along w ----
    const int sr = l >> 4;           // c-pair row [0,4)
    const int ss = l & 15;           // w sub-slot

    float4 R2[8];                    // x2 in flight (next chunk)
    auto issueX2 = [&](int c0) {
        #pragma unroll
        for (int k = 0; k < 4; ++k) {
            const float* g = x2g + (c0 + 2 * sr) * HW + 4 * (ss + 16 * k);
            R2[2 * k]     = *(const float4*)g;          // channel c0+2sr
            R2[2 * k + 1] = *(const float4*)(g + HW);   // channel c0+2sr+1
        }
    };
    auto commitX2 = [&](int bufi) {
        #pragma unroll
        for (int k = 0; k < 4; ++k) {
            uint4 p;
            p.x = pack2(R2[2 * k].x, R2[2 * k + 1].x);
            p.y = pack2(R2[2 * k].y, R2[2 * k + 1].y);
            p.z = pack2(R2[2 * k].z, R2[2 * k + 1].z);
            p.w = pack2(R2[2 * k].w, R2[2 * k + 1].w);
            *(uint4*)&x2h[bufi][sr][64 + 4 * (ss + 16 * k)] = p;
        }
    };

    // ---- x1 staging: packed regs, half-chunk-ahead pipeline ----
    float4 R1[4];                    // two c-pairs in flight
    unsigned int aw[4][4];           // current chunk, aw[c2][wl]
    auto issueX1 = [&](int c0, int p0) {     // pairs p0, p0+1
        #pragma unroll
        for (int pp = 0; pp < 2; ++pp) {
            const float* g = x1g + (c0 + 2 * (p0 + pp)) * HW + 4 * l;
            R1[2 * pp]     = *(const float4*)g;
            R1[2 * pp + 1] = *(const float4*)(g + HW);
        }
    };
    auto packX1 = [&](int p0) {              // R1 -> aw[p0], aw[p0+1]
        #pragma unroll
        for (int pp = 0; pp < 2; ++pp) {
            const float4 lo = R1[2 * pp], hi = R1[2 * pp + 1];
            aw[p0 + pp][0] = pack2(lo.x, hi.x);
            aw[p0 + pp][1] = pack2(lo.y, hi.y);
            aw[p0 + pp][2] = pack2(lo.z, hi.z);
            aw[p0 + pp][3] = pack2(lo.w, hi.w);
        }
    };

    auto computeC2 = [&](int bufi, int c2) {
        const uint4 b0 = *(const uint4*)&x2h[bufi][c2][j0a];
        const uint4 b1 = *(const uint4*)&x2h[bufi][c2][j0a + 4];
        const uint4 b2 = *(const uint4*)&x2h[bufi][c2][j0a + 8];
        const uint4 b3 = *(const uint4*)&x2h[bufi][c2][j0a + 12];
        const uint4 b4 = *(const uint4*)&x2h[bufi][c2][j0a + 16];
        const unsigned int bw[20] = {b0.x, b0.y, b0.z, b0.w,
                                     b1.x, b1.y, b1.z, b1.w,
                                     b2.x, b2.y, b2.z, b2.w,
                                     b3.x, b3.y, b3.z, b3.w,
                                     b4.x, b4.y, b4.z, b4.w};
        #pragma unroll
        for (int il = 0; il < 16; ++il)
            #pragma unroll
            for (int wl = 0; wl < 4; ++wl)
                acc[il][wl] = fdot2f(aw[c2][wl], bw[16 + wl - il], acc[il][wl]);
        if (qi == 3) {   // i == 64: window idx wl
            #pragma unroll
            for (int wl = 0; wl < 4; ++wl)
                acc64[wl] = fdot2f(aw[c2][wl], bw[wl], acc64[wl]);
        }
    };

    // ---- prologue: fill buf0 + pack chunk-0 x1 (one-time latency) ----
    issueX2(0);
    issueX1(0, 0);
    commitX2(0);
    packX1(0);
    issueX1(0, 2);
    packX1(2);
    asm volatile("" ::: "memory");

    // ---- main loop: one wave, zero barriers ----
    for (int t = 0; t < NCHUNK; ++t) {
        const int cur  = t & 1;
        const int c0n  = (t + 1) * 2 * KC2;
        const bool more = (t + 1 < NCHUNK);

        if (more) { issueX2(c0n); issueX1(c0n, 0); }
        asm volatile("" ::: "memory");

        computeC2(cur, 0);
        computeC2(cur, 1);

        if (more) { packX1(0); issueX1(c0n, 2); }   // aw[0,1] <- next chunk
        asm volatile("" ::: "memory");

        computeC2(cur, 2);
        computeC2(cur, 3);

        if (more) {
            commitX2(cur ^ 1);   // vmcnt drain lands here, after compute
            packX1(2);           // aw[2,3] <- next chunk
        }
        asm volatile("" ::: "memory");
    }

    // ---- epilogue: out[n, i, h, w], lane-contiguous float4 stores ----
    const float scale = 1.0f / (float)C;
    float* outg = out + n * (NI * HW) + h * W + 4 * l;
    #pragma unroll
    for (int il = 0; il < 16; ++il) {
        const int i = 16 * qi + il;
        *(float4*)(outg + i * HW) =
            make_float4(acc[il][0] * scale, acc[il][1] * scale,
                        acc[il][2] * scale, acc[il][3] * scale);
    }
    if (qi == 3) {
        *(float4*)(outg + 64 * HW) =
            make_float4(acc64[0] * scale, acc64[1] * scale,
                        acc64[2] * scale, acc64[3] * scale);
    }
}

extern "C" void kernel_launch(void* const* d_in, const int* in_sizes, int n_in,
                              void* d_out, int out_size, void* d_ws, size_t ws_size,
                              hipStream_t stream) {
    const float* x1 = (const float*)d_in[0];
    const float* x2 = (const float*)d_in[1];
    float* out = (float*)d_out;
    dim3 grid(4, H, B);   // (qi, h, n) = 4096 single-wave blocks
    corr_volume_kernel<<<grid, 64, 0, stream>>>(x1, x2, out);
}

// Round 7
// 322.344 us; speedup vs baseline: 2.6001x; 2.6001x over previous
//
#include <hip/hip_runtime.h>

// CorrVolume1DBlock: cv[n,i,h,w] = (1/C) * sum_c x1[n,c,h,w] * x2[n,c,h,w-i],
// zero where w-i < 0.  B=8, C=128, H=128, W=256, i in [0,64], fp32 in/out.
//
// R11 == R10 resubmitted (R10 bench was an infra failure: "container failed
// twice", no counters; kernel re-audited - gload_lds contract, races, bounds
// all verified sound).
//
// R10: global_load_lds streaming. Evidence so far: every reg-staged variant
// pins at 1.5 TB/s because the compiler sinks the staging loads to their
// commit site (R6: VGPR=64) -> full latency exposed per chunk; R9's
// barrier-free waves hit 2.9 TB/s but spilled (973 MB scratch writes).
// Fix: stage with __builtin_amdgcn_global_load_lds (direct HBM->LDS DMA,
// no register destination to sink, m97-verified early-issue behavior):
//  - f32 in LDS (DMA can't convert) + plain fmaf compute. VALU floor is
//    only ~14 us (4 SIMDs/CU), so dropping fdot2 is free; absmax ~1e-5.
//  - 512 thr = 8 waves per (n,h); wave q owns i in [8q,8q+8), wave 0 also
//    i=64. acc[8][4]+acc64 = 36 f32/thread -- no spill risk.
//  - double-buffered LDS 72 KB (x1 2x16x256, x2 2x16x320 w/ 64-col zero
//    margin) -> 2 blocks/CU, 4 waves/SIMD (__launch_bounds__(512,4)).
//  - ONE barrier per chunk: stage(t+1 -> buf^1) issued BEFORE compute(t);
//    the compiler's vmcnt(0)+barrier drain lands ~12K cycles later (free).
//    WAR on buf^1 is protected by the previous chunk's barrier.
//  - per-CU per-chunk: LDS-read 12.7K cyc (binding), HBM 7.2K (hidden),
//    VALU 4K. Target ~16K cyc/chunk x 8 = ~55-80 us.
//  - all LDS ops b128 at 16 B lane stride; gload_lds dest = uniform row
//    base + lane*16 (linear, matches layout - guide m104 constraint).

constexpr int B   = 8;
constexpr int C   = 128;
constexpr int H   = 128;
constexpr int W   = 256;
constexpr int NI  = 65;
constexpr int HW  = H * W;
constexpr int CHW = C * HW;
constexpr int KC  = 16;              // channels per chunk
constexpr int X2W = 320;             // x2 cols: j in [0,320) <-> w' = j-64
constexpr int NCHUNK = C / KC;       // 8

__global__ __launch_bounds__(512, 4)
void corr_volume_kernel(const float* __restrict__ x1,
                        const float* __restrict__ x2,
                        float* __restrict__ out) {
    const int h   = blockIdx.x;
    const int n   = blockIdx.y;
    const int tid = threadIdx.x;
    const int l   = tid & 63;        // w = 4l .. 4l+3
    const int q   = tid >> 6;        // wave q: i = 8q .. 8q+7; q==0 also i=64

    __shared__ float x1h[2][KC][W];      // 32 KB
    __shared__ float x2h[2][KC][X2W];    // 40 KB  (72 KB total -> 2 blocks/CU)

    float acc[8][4];
    #pragma unroll
    for (int il = 0; il < 8; ++il)
        #pragma unroll
        for (int wl = 0; wl < 4; ++wl) acc[il][wl] = 0.0f;
    float acc64[4] = {0.f, 0.f, 0.f, 0.f};

    // window: col j = w - i + 64 = j0m8 + (8 + wl - il), idx in [1,11];
    // 3 aligned float4 per channel. j0m8 in [0,308].
    const int j0m8 = 4 * l - 8 * q + 56;

    const float* x1g = x1 + n * CHW + h * W;
    const float* x2g = x2 + n * CHW + h * W;

    // zero-fill left margins of both buffers: 2 bufs x 16 rows x 16 float4
    // = 512 slots = exactly one per thread. (never overwritten afterwards)
    {
        const int bufi = tid >> 8;          // [0,2)
        const int rr   = (tid >> 4) & 15;   // [0,16)
        const int cq   = tid & 15;          // cols [0,64)
        *(float4*)&x2h[bufi][rr][4 * cq] = make_float4(0.f, 0.f, 0.f, 0.f);
    }

    // stage chunk t into buffer bufi: wave q DMAs x1 rows {q,q+8} and
    // x2 rows {q,q+8}. Dest = uniform row base; HW adds lane*16 (linear).
    auto stage = [&](int t, int bufi) {
        const int c0 = t * KC;
        #pragma unroll
        for (int rr = 0; rr < 2; ++rr) {
            const int r = q + 8 * rr;
            const float* g1 = x1g + (c0 + r) * HW + 4 * l;   // per-lane src
            const float* g2 = x2g + (c0 + r) * HW + 4 * l;
            __builtin_amdgcn_global_load_lds(
                (const __attribute__((address_space(1))) void*)g1,
                (__attribute__((address_space(3))) void*)&x1h[bufi][r][0],
                16, 0, 0);
            __builtin_amdgcn_global_load_lds(
                (const __attribute__((address_space(1))) void*)g2,
                (__attribute__((address_space(3))) void*)&x2h[bufi][r][64],
                16, 0, 0);
        }
    };

    // prologue: fill buffer 0 (one-time cold latency)
    stage(0, 0);
    __syncthreads();   // compiler emits s_waitcnt vmcnt(0) before s_barrier

    for (int t = 0; t < NCHUNK; ++t) {
        const int cur = t & 1;

        // issue next chunk's DMA first: no register destination, cannot be
        // sunk; completes under the ~12K cycles of compute below.
        if (t + 1 < NCHUNK) stage(t + 1, cur ^ 1);

        #pragma unroll 4
        for (int c = 0; c < KC; ++c) {
            const float4 a4 = *(const float4*)&x1h[cur][c][4 * l];
            const float aw[4] = {a4.x, a4.y, a4.z, a4.w};
            const float4 b0 = *(const float4*)&x2h[cur][c][j0m8];
            const float4 b1 = *(const float4*)&x2h[cur][c][j0m8 + 4];
            const float4 b2 = *(const float4*)&x2h[cur][c][j0m8 + 8];
            const float bw[12] = {b0.x, b0.y, b0.z, b0.w,
                                  b1.x, b1.y, b1.z, b1.w,
                                  b2.x, b2.y, b2.z, b2.w};
            #pragma unroll
            for (int il = 0; il < 8; ++il)
                #pragma unroll
                for (int wl = 0; wl < 4; ++wl)
                    acc[il][wl] = fmaf(aw[wl], bw[8 + wl - il], acc[il][wl]);

            if (q == 0) {   // i == 64: col j = w = 4l+wl (margin gives w<64 -> 0)
                const float4 d = *(const float4*)&x2h[cur][c][4 * l];
                const float dw[4] = {d.x, d.y, d.z, d.w};
                #pragma unroll
                for (int wl = 0; wl < 4; ++wl)
                    acc64[wl] = fmaf(aw[wl], dw[wl], acc64[wl]);
            }
        }

        // one barrier per chunk: drains this wave's DMA (issued ~12K cyc ago,
        // i.e. ~free) and orders buf reuse across waves.
        __syncthreads();
    }

    // ---- epilogue: out[n, i, h, w], lane-contiguous float4 stores ----
    const float scale = 1.0f / (float)C;
    float* outg = out + n * (NI * HW) + h * W + 4 * l;
    #pragma unroll
    for (int il = 0; il < 8; ++il) {
        const int i = 8 * q + il;
        *(float4*)(outg + i * HW) =
            make_float4(acc[il][0] * scale, acc[il][1] * scale,
                        acc[il][2] * scale, acc[il][3] * scale);
    }
    if (q == 0) {
        *(float4*)(outg + 64 * HW) =
            make_float4(acc64[0] * scale, acc64[1] * scale,
                        acc64[2] * scale, acc64[3] * scale);
    }
}

extern "C" void kernel_launch(void* const* d_in, const int* in_sizes, int n_in,
                              void* d_out, int out_size, void* d_ws, size_t ws_size,
                              hipStream_t stream) {
    const float* x1 = (const float*)d_in[0];
    const float* x2 = (const float*)d_in[1];
    float* out = (float*)d_out;
    dim3 grid(H, B);   // 1024 blocks, one per (n, h); 2 resident/CU
    corr_volume_kernel<<<grid, 512, 0, stream>>>(x1, x2, out);
}